// Round 12
// baseline (274.883 us; speedup 1.0000x reference)
//
#include <hip/hip_runtime.h>

// BERTSyntaxRel: B=32 S=1024 D=768 H=128 R=48
// out[t,r] = sum_{h,k} head[t,h] * kern[h, r*128+k] * tail[t,k]
//          = (Z @ K2)[t, r]   with Z[t, hk] = head[t,h]*tail[t,k]  (rank-1 rows)
// prep_kernel: kern -> f16 MFMA B-frags (Bp)
// prep_w:      Wh/Wt -> f16 MFMA B-frags (Whp/Wtp)
// ff_mfma:     FF via MFMA; latency fix (r9): n-split across 2x waves (grid.y=4)
//              + explicit 1-deep x prefetch, __launch_bounds__(256,8)
// biaffine_mfma: Z@K2 via MFMA, A-frags in-register, k-split + LDS reduce

#define BB 32
#define SS 1024
#define DD 768
#define HH 128
#define RR 48
#define NTOK (BB * SS)

typedef _Float16 f16;
typedef _Float16 f16x8 __attribute__((ext_vector_type(8)));
typedef float f32x4 __attribute__((ext_vector_type(4)));

// ---------------- prep: pack kernel (f32 128x6144) into f16 B-frags ----------
// Bp[(((h*4+kw)*3+n)*64+l)*8+j] = kern[h][(n*16+(l&15))*128 + kw*32 + (l>>4)*8 + j]
__global__ __launch_bounds__(256) void prep_kernel(
    const float* __restrict__ kern, f16* __restrict__ Bp)
{
    const int idx = blockIdx.x * 256 + threadIdx.x;   // < 786432
    const int j = idx & 7;
    const int l = (idx >> 3) & 63;
    int rem = idx >> 9;
    const int n = rem % 3;
    rem /= 3;
    const int kw = rem & 3;
    const int h = rem >> 2;
    const int r = n * 16 + (l & 15);
    const int k = kw * 32 + (l >> 4) * 8 + j;
    Bp[idx] = (f16)kern[(size_t)h * (RR * HH) + (size_t)r * HH + k];
}

// ---------------- prep_w: pack W (f32 768x128) into f16 B-frags ----------
// Wp[((s*8+n)*64+l)*8+j] = W[(s*32+(l>>4)*8+j)*128 + n*16+(l&15)]
__global__ __launch_bounds__(256) void prep_w(
    const float* __restrict__ Wh, const float* __restrict__ Wt,
    f16* __restrict__ Whp, f16* __restrict__ Wtp)
{
    const int idx = blockIdx.x * 256 + threadIdx.x;   // < 98304
    const float* __restrict__ W = blockIdx.y ? Wt : Wh;
    f16* __restrict__ Wp        = blockIdx.y ? Wtp : Whp;
    const int j = idx & 7;
    const int l = (idx >> 3) & 63;
    const int rem = idx >> 9;
    const int n = rem & 7;
    const int s = rem >> 3;
    const int k = s * 32 + (l >> 4) * 8 + j;
    const int c = n * 16 + (l & 15);
    Wp[idx] = (f16)W[(size_t)k * HH + c];
}

// ---------------- FF via MFMA: M=NTOK N=128 K=768 ----------------
// block = 256 thr (4 waves) = 64 tokens; wave = 16-token tile x 4 n-tiles.
// grid.y: bit0 = branch (0 head / 1 tail), bit1 = n-half (n0 = (y>>1)*4).
// A-frag: lane l -> row tok0+(l&15), k=(l>>4)*8+j (f32 load + cvt),
// 1-deep explicit prefetch; 8192 waves -> full occupancy for latency hiding.
__global__ __launch_bounds__(256, 8) void ff_mfma(
    const float* __restrict__ x, const int* __restrict__ head_id,
    const float* __restrict__ root,
    const f16* __restrict__ Whp, const float* __restrict__ bh,
    const f16* __restrict__ Wtp, const float* __restrict__ bt,
    f16* __restrict__ headm, f16* __restrict__ tailm)
{
    const int tid  = threadIdx.x;
    const int lane = tid & 63;
    const int w    = tid >> 6;
    const bool is_head = ((blockIdx.y & 1) == 0);
    const int nh = blockIdx.y >> 1;           // n-half: n-tiles nh*4 .. nh*4+3

    const f16*   __restrict__ Wp   = is_head ? Whp : Wtp;
    const float* __restrict__ bias = is_head ? bh : bt;
    f16*         __restrict__ outm = is_head ? headm : tailm;

    const int lr = lane & 15;
    const int lg = lane >> 4;
    const int tok0 = blockIdx.x * 64 + w * 16;
    const int tk = tok0 + lr;

    const float* srcrow;
    if (is_head) {
        const int hid = head_id[tk];
        const int b = tk >> 10;
        srcrow = (hid == 0) ? root : (x + ((size_t)(b * SS + hid - 1)) * DD);
    } else {
        srcrow = x + (size_t)tk * DD;
    }
    srcrow += lg * 8;

    f32x4 acc[4];
    #pragma unroll
    for (int n = 0; n < 4; ++n) acc[n] = (f32x4)0.f;

    float4 ca0 = *(const float4*)(srcrow);
    float4 ca1 = *(const float4*)(srcrow + 4);

    #pragma unroll
    for (int s = 0; s < DD / 32; ++s) {        // 24 K-steps, 1-deep prefetch
        float4 na0, na1;
        if (s + 1 < DD / 32) {
            na0 = *(const float4*)(srcrow + (s + 1) * 32);
            na1 = *(const float4*)(srcrow + (s + 1) * 32 + 4);
        }
        f16x8 af;
        af[0] = (f16)ca0.x; af[1] = (f16)ca0.y; af[2] = (f16)ca0.z; af[3] = (f16)ca0.w;
        af[4] = (f16)ca1.x; af[5] = (f16)ca1.y; af[6] = (f16)ca1.z; af[7] = (f16)ca1.w;

        const f16* bp = Wp + (size_t)(s * 8 + nh * 4) * 512 + lane * 8;
        #pragma unroll
        for (int n = 0; n < 4; ++n) {
            const f16x8 bf = *(const f16x8*)(bp + n * 512);
            acc[n] = __builtin_amdgcn_mfma_f32_16x16x32_f16(af, bf, acc[n], 0, 0, 0);
        }
        ca0 = na0; ca1 = na1;
    }

    float bv[4];
    #pragma unroll
    for (int n = 0; n < 4; ++n) bv[n] = bias[(nh * 4 + n) * 16 + lr];

    // C layout: col = lane&15 (-> h = (nh*4+n)*16+lr), row = (lane>>4)*4 + wi
    #pragma unroll
    for (int wi = 0; wi < 4; ++wi) {
        const int tr = tok0 + lg * 4 + wi;
        #pragma unroll
        for (int n = 0; n < 4; ++n)
            outm[(size_t)tr * HH + (nh * 4 + n) * 16 + lr] =
                (f16)fmaxf(acc[n][wi] + bv[n], 0.f);
    }
}

// ---------------- biaffine via MFMA ----------------
// block = 512 thr (8 waves) = 128 tokens; wave (g = tile-group of 4, q = h-quarter)
__global__ __launch_bounds__(512, 2) void biaffine_mfma(
    const f16* __restrict__ headm, const f16* __restrict__ tailm,
    const f16* __restrict__ Bp, float* __restrict__ out)
{
    __shared__ float red[6 * 12 * 4 * 64];   // 73.7 KB

    const int tid  = threadIdx.x;
    const int lane = tid & 63;
    const int wv   = tid >> 6;
    const int g    = wv & 1;      // tile-group
    const int q    = wv >> 1;     // h-quarter
    const int lr   = lane & 15;
    const int lg   = lane >> 4;
    const int tok0 = blockIdx.x * 128 + g * 64;

    f16x8 hrv[4][4];   // [tile][c]: h = q*32 + c*8 + e
    f16x8 trg[4][4];   // [tile][kw]: k = kw*32 + lg*8 + j
    #pragma unroll
    for (int i = 0; i < 4; ++i) {
        const f16* hp = headm + (size_t)(tok0 + i * 16 + lr) * HH + q * 32;
        const f16* tp = tailm + (size_t)(tok0 + i * 16 + lr) * HH + lg * 8;
        #pragma unroll
        for (int c = 0; c < 4; ++c)  hrv[i][c]  = *(const f16x8*)(hp + c * 8);
        #pragma unroll
        for (int kw = 0; kw < 4; ++kw) trg[i][kw] = *(const f16x8*)(tp + kw * 32);
    }

    f32x4 acc[4][3];
    #pragma unroll
    for (int i = 0; i < 4; ++i)
        #pragma unroll
        for (int n = 0; n < 3; ++n) acc[i][n] = (f32x4)0.f;

    const f16* bq = Bp + (size_t)(q * 32) * 6144;

    #pragma unroll
    for (int h = 0; h < 32; ++h) {
        f16 hs[4];
        #pragma unroll
        for (int i = 0; i < 4; ++i) hs[i] = hrv[i][h >> 3][h & 7];

        #pragma unroll
        for (int kw = 0; kw < 4; ++kw) {
            const f16* bp = bq + ((size_t)(h * 4 + kw) * 3) * 512 + lane * 8;
            f16x8 bf0 = *(const f16x8*)(bp);
            f16x8 bf1 = *(const f16x8*)(bp + 512);
            f16x8 bf2 = *(const f16x8*)(bp + 1024);
            #pragma unroll
            for (int i = 0; i < 4; ++i) {
                const f16x8 af = hs[i] * trg[i][kw];   // v_pk_mul_f16 x4
                acc[i][0] = __builtin_amdgcn_mfma_f32_16x16x32_f16(af, bf0, acc[i][0], 0, 0, 0);
                acc[i][1] = __builtin_amdgcn_mfma_f32_16x16x32_f16(af, bf1, acc[i][1], 0, 0, 0);
                acc[i][2] = __builtin_amdgcn_mfma_f32_16x16x32_f16(af, bf2, acc[i][2], 0, 0, 0);
            }
        }
    }

    if (q > 0) {
        const int reg = (q - 1) * 2 + g;
        #pragma unroll
        for (int i = 0; i < 4; ++i)
            #pragma unroll
            for (int n = 0; n < 3; ++n)
                #pragma unroll
                for (int w = 0; w < 4; ++w)
                    red[((reg * 12 + i * 3 + n) * 4 + w) * 64 + lane] = acc[i][n][w];
    }
    __syncthreads();
    if (q == 0) {
        #pragma unroll
        for (int qq = 1; qq < 4; ++qq) {
            const int reg = (qq - 1) * 2 + g;
            #pragma unroll
            for (int i = 0; i < 4; ++i)
                #pragma unroll
                for (int n = 0; n < 3; ++n)
                    #pragma unroll
                    for (int w = 0; w < 4; ++w)
                        acc[i][n][w] += red[((reg * 12 + i * 3 + n) * 4 + w) * 64 + lane];
        }
        #pragma unroll
        for (int i = 0; i < 4; ++i)
            #pragma unroll
            for (int n = 0; n < 3; ++n)
                #pragma unroll
                for (int w = 0; w < 4; ++w)
                    out[(size_t)(tok0 + i * 16 + lg * 4 + w) * RR + n * 16 + lr] = acc[i][n][w];
    }
}

extern "C" void kernel_launch(void* const* d_in, const int* in_sizes, int n_in,
                              void* d_out, int out_size, void* d_ws, size_t ws_size,
                              hipStream_t stream)
{
    const float* x    = (const float*)d_in[0];
    const int*   hid  = (const int*)d_in[1];
    const float* root = (const float*)d_in[2];
    const float* Wh   = (const float*)d_in[3];
    const float* bh   = (const float*)d_in[4];
    const float* Wt   = (const float*)d_in[5];
    const float* bt   = (const float*)d_in[6];
    const float* kern = (const float*)d_in[7];
    float* out = (float*)d_out;

    // ws: headm (8.39 MB) + tailm (8.39 MB) + Bp (1.57 MB) + Whp/Wtp (196 KB each)
    f16* headm = (f16*)d_ws;
    f16* tailm = headm + (size_t)NTOK * HH;
    f16* Bp    = tailm + (size_t)NTOK * HH;
    f16* Whp   = Bp + (size_t)HH * RR * HH;
    f16* Wtp   = Whp + (size_t)(DD / 32) * 8 * 512;

    prep_kernel<<<(HH * RR * HH) / 256, 256, 0, stream>>>(kern, Bp);
    dim3 wgrid((DD / 32) * 8 * 512 / 256, 2);
    prep_w<<<wgrid, 256, 0, stream>>>(Wh, Wt, Whp, Wtp);
    dim3 ffgrid(NTOK / 64, 4);
    ff_mfma<<<ffgrid, 256, 0, stream>>>(x, hid, root, Whp, bh, Wtp, bt, headm, tailm);
    biaffine_mfma<<<NTOK / 128, 512, 0, stream>>>(headm, tailm, Bp, out);
}

// Round 13
// 260.678 us; speedup vs baseline: 1.0545x; 1.0545x over previous
//
#include <hip/hip_runtime.h>

// BERTSyntaxRel: B=32 S=1024 D=768 H=128 R=48
// out[t,r] = sum_{h,k} head[t,h] * kern[h, r*128+k] * tail[t,k]
//          = (Z @ K2)[t, r]   with Z[t, hk] = head[t,h]*tail[t,k]  (rank-1 rows)
// prep_kernel: kern -> f16 MFMA B-frags (Bp)
// prep_w:      Wh/Wt -> f16 MFMA B-frags (Whp/Wtp)
// ff_mfma:     FF via MFMA; r12 revert n-split (FETCH 2x regression);
//              r13: software pipeline — B-frags 1-deep, A-loads 2-deep
// biaffine_mfma: Z@K2 via MFMA, A-frags in-register, k-split + LDS reduce

#define BB 32
#define SS 1024
#define DD 768
#define HH 128
#define RR 48
#define NTOK (BB * SS)

typedef _Float16 f16;
typedef _Float16 f16x8 __attribute__((ext_vector_type(8)));
typedef float f32x4 __attribute__((ext_vector_type(4)));

// ---------------- prep: pack kernel (f32 128x6144) into f16 B-frags ----------
// Bp[(((h*4+kw)*3+n)*64+l)*8+j] = kern[h][(n*16+(l&15))*128 + kw*32 + (l>>4)*8 + j]
__global__ __launch_bounds__(256) void prep_kernel(
    const float* __restrict__ kern, f16* __restrict__ Bp)
{
    const int idx = blockIdx.x * 256 + threadIdx.x;   // < 786432
    const int j = idx & 7;
    const int l = (idx >> 3) & 63;
    int rem = idx >> 9;
    const int n = rem % 3;
    rem /= 3;
    const int kw = rem & 3;
    const int h = rem >> 2;
    const int r = n * 16 + (l & 15);
    const int k = kw * 32 + (l >> 4) * 8 + j;
    Bp[idx] = (f16)kern[(size_t)h * (RR * HH) + (size_t)r * HH + k];
}

// ---------------- prep_w: pack W (f32 768x128) into f16 B-frags ----------
// Wp[((s*8+n)*64+l)*8+j] = W[(s*32+(l>>4)*8+j)*128 + n*16+(l&15)]
__global__ __launch_bounds__(256) void prep_w(
    const float* __restrict__ Wh, const float* __restrict__ Wt,
    f16* __restrict__ Whp, f16* __restrict__ Wtp)
{
    const int idx = blockIdx.x * 256 + threadIdx.x;   // < 98304
    const float* __restrict__ W = blockIdx.y ? Wt : Wh;
    f16* __restrict__ Wp        = blockIdx.y ? Wtp : Whp;
    const int j = idx & 7;
    const int l = (idx >> 3) & 63;
    const int rem = idx >> 9;
    const int n = rem & 7;
    const int s = rem >> 3;
    const int k = s * 32 + (l >> 4) * 8 + j;
    const int c = n * 16 + (l & 15);
    Wp[idx] = (f16)W[(size_t)k * HH + c];
}

// ---------------- FF via MFMA: M=NTOK N=128 K=768 ----------------
// block = 256 thr (4 waves) = 64 tokens; wave = 16-token tile x all 8 n-tiles
// (single x pass). grid.y = branch. Software pipeline: per K-step issue the
// next step's 8 B-frags (L2) and the s+2 A-row chunk (HBM/L3) before this
// step's MFMAs -> ~12 outstanding loads/wave to cover latency.
__global__ __launch_bounds__(256) void ff_mfma(
    const float* __restrict__ x, const int* __restrict__ head_id,
    const float* __restrict__ root,
    const f16* __restrict__ Whp, const float* __restrict__ bh,
    const f16* __restrict__ Wtp, const float* __restrict__ bt,
    f16* __restrict__ headm, f16* __restrict__ tailm)
{
    const int tid  = threadIdx.x;
    const int lane = tid & 63;
    const int w    = tid >> 6;
    const bool is_head = (blockIdx.y == 0);

    const f16*   __restrict__ Wp   = is_head ? Whp : Wtp;
    const float* __restrict__ bias = is_head ? bh : bt;
    f16*         __restrict__ outm = is_head ? headm : tailm;

    const int lr = lane & 15;
    const int lg = lane >> 4;
    const int tok0 = blockIdx.x * 64 + w * 16;
    const int tk = tok0 + lr;

    const float* srcrow;
    if (is_head) {
        const int hid = head_id[tk];
        const int b = tk >> 10;
        srcrow = (hid == 0) ? root : (x + ((size_t)(b * SS + hid - 1)) * DD);
    } else {
        srcrow = x + (size_t)tk * DD;
    }
    srcrow += lg * 8;

    const f16* bbase = Wp + lane * 8;

    f32x4 acc[8];
    #pragma unroll
    for (int n = 0; n < 8; ++n) acc[n] = (f32x4)0.f;

    // pipeline prologue: A for s=0,1; B for s=0
    float4 aA0 = *(const float4*)(srcrow);
    float4 aA1 = *(const float4*)(srcrow + 4);
    float4 aB0 = *(const float4*)(srcrow + 32);
    float4 aB1 = *(const float4*)(srcrow + 36);

    f16x8 bcur[8], bnext[8];
    #pragma unroll
    for (int n = 0; n < 8; ++n)
        bcur[n] = *(const f16x8*)(bbase + (size_t)n * 512);

    #pragma unroll
    for (int s = 0; s < DD / 32; ++s) {        // 24 K-steps
        // issue next-step B-frags (L2, 8 x 16B)
        if (s + 1 < DD / 32) {
            #pragma unroll
            for (int n = 0; n < 8; ++n)
                bnext[n] = *(const f16x8*)(bbase + (size_t)((s + 1) * 8 + n) * 512);
        }
        // issue s+2 A chunk (HBM/L3)
        float4 aC0, aC1;
        if (s + 2 < DD / 32) {
            aC0 = *(const float4*)(srcrow + (s + 2) * 32);
            aC1 = *(const float4*)(srcrow + (s + 2) * 32 + 4);
        }
        // consume current A + B
        f16x8 af;
        af[0] = (f16)aA0.x; af[1] = (f16)aA0.y; af[2] = (f16)aA0.z; af[3] = (f16)aA0.w;
        af[4] = (f16)aA1.x; af[5] = (f16)aA1.y; af[6] = (f16)aA1.z; af[7] = (f16)aA1.w;

        #pragma unroll
        for (int n = 0; n < 8; ++n)
            acc[n] = __builtin_amdgcn_mfma_f32_16x16x32_f16(af, bcur[n], acc[n], 0, 0, 0);

        // static rotation (register renaming, no scratch)
        aA0 = aB0; aA1 = aB1; aB0 = aC0; aB1 = aC1;
        #pragma unroll
        for (int n = 0; n < 8; ++n) bcur[n] = bnext[n];
    }

    float bv[8];
    #pragma unroll
    for (int n = 0; n < 8; ++n) bv[n] = bias[n * 16 + lr];

    // C layout: col = lane&15 (-> h = n*16+lr), row = (lane>>4)*4 + wi (-> token)
    #pragma unroll
    for (int wi = 0; wi < 4; ++wi) {
        const int tr = tok0 + lg * 4 + wi;
        #pragma unroll
        for (int n = 0; n < 8; ++n)
            outm[(size_t)tr * HH + n * 16 + lr] = (f16)fmaxf(acc[n][wi] + bv[n], 0.f);
    }
}

// ---------------- biaffine via MFMA ----------------
// block = 512 thr (8 waves) = 128 tokens; wave (g = tile-group of 4, q = h-quarter)
__global__ __launch_bounds__(512, 2) void biaffine_mfma(
    const f16* __restrict__ headm, const f16* __restrict__ tailm,
    const f16* __restrict__ Bp, float* __restrict__ out)
{
    __shared__ float red[6 * 12 * 4 * 64];   // 73.7 KB

    const int tid  = threadIdx.x;
    const int lane = tid & 63;
    const int wv   = tid >> 6;
    const int g    = wv & 1;      // tile-group
    const int q    = wv >> 1;     // h-quarter
    const int lr   = lane & 15;
    const int lg   = lane >> 4;
    const int tok0 = blockIdx.x * 128 + g * 64;

    f16x8 hrv[4][4];   // [tile][c]: h = q*32 + c*8 + e
    f16x8 trg[4][4];   // [tile][kw]: k = kw*32 + lg*8 + j
    #pragma unroll
    for (int i = 0; i < 4; ++i) {
        const f16* hp = headm + (size_t)(tok0 + i * 16 + lr) * HH + q * 32;
        const f16* tp = tailm + (size_t)(tok0 + i * 16 + lr) * HH + lg * 8;
        #pragma unroll
        for (int c = 0; c < 4; ++c)  hrv[i][c]  = *(const f16x8*)(hp + c * 8);
        #pragma unroll
        for (int kw = 0; kw < 4; ++kw) trg[i][kw] = *(const f16x8*)(tp + kw * 32);
    }

    f32x4 acc[4][3];
    #pragma unroll
    for (int i = 0; i < 4; ++i)
        #pragma unroll
        for (int n = 0; n < 3; ++n) acc[i][n] = (f32x4)0.f;

    const f16* bq = Bp + (size_t)(q * 32) * 6144;

    #pragma unroll
    for (int h = 0; h < 32; ++h) {
        f16 hs[4];
        #pragma unroll
        for (int i = 0; i < 4; ++i) hs[i] = hrv[i][h >> 3][h & 7];

        #pragma unroll
        for (int kw = 0; kw < 4; ++kw) {
            const f16* bp = bq + ((size_t)(h * 4 + kw) * 3) * 512 + lane * 8;
            f16x8 bf0 = *(const f16x8*)(bp);
            f16x8 bf1 = *(const f16x8*)(bp + 512);
            f16x8 bf2 = *(const f16x8*)(bp + 1024);
            #pragma unroll
            for (int i = 0; i < 4; ++i) {
                const f16x8 af = hs[i] * trg[i][kw];   // v_pk_mul_f16 x4
                acc[i][0] = __builtin_amdgcn_mfma_f32_16x16x32_f16(af, bf0, acc[i][0], 0, 0, 0);
                acc[i][1] = __builtin_amdgcn_mfma_f32_16x16x32_f16(af, bf1, acc[i][1], 0, 0, 0);
                acc[i][2] = __builtin_amdgcn_mfma_f32_16x16x32_f16(af, bf2, acc[i][2], 0, 0, 0);
            }
        }
    }

    if (q > 0) {
        const int reg = (q - 1) * 2 + g;
        #pragma unroll
        for (int i = 0; i < 4; ++i)
            #pragma unroll
            for (int n = 0; n < 3; ++n)
                #pragma unroll
                for (int w = 0; w < 4; ++w)
                    red[((reg * 12 + i * 3 + n) * 4 + w) * 64 + lane] = acc[i][n][w];
    }
    __syncthreads();
    if (q == 0) {
        #pragma unroll
        for (int qq = 1; qq < 4; ++qq) {
            const int reg = (qq - 1) * 2 + g;
            #pragma unroll
            for (int i = 0; i < 4; ++i)
                #pragma unroll
                for (int n = 0; n < 3; ++n)
                    #pragma unroll
                    for (int w = 0; w < 4; ++w)
                        acc[i][n][w] += red[((reg * 12 + i * 3 + n) * 4 + w) * 64 + lane];
        }
        #pragma unroll
        for (int i = 0; i < 4; ++i)
            #pragma unroll
            for (int n = 0; n < 3; ++n)
                #pragma unroll
                for (int w = 0; w < 4; ++w)
                    out[(size_t)(tok0 + i * 16 + lg * 4 + w) * RR + n * 16 + lr] = acc[i][n][w];
    }
}

extern "C" void kernel_launch(void* const* d_in, const int* in_sizes, int n_in,
                              void* d_out, int out_size, void* d_ws, size_t ws_size,
                              hipStream_t stream)
{
    const float* x    = (const float*)d_in[0];
    const int*   hid  = (const int*)d_in[1];
    const float* root = (const float*)d_in[2];
    const float* Wh   = (const float*)d_in[3];
    const float* bh   = (const float*)d_in[4];
    const float* Wt   = (const float*)d_in[5];
    const float* bt   = (const float*)d_in[6];
    const float* kern = (const float*)d_in[7];
    float* out = (float*)d_out;

    // ws: headm (8.39 MB) + tailm (8.39 MB) + Bp (1.57 MB) + Whp/Wtp (196 KB each)
    f16* headm = (f16*)d_ws;
    f16* tailm = headm + (size_t)NTOK * HH;
    f16* Bp    = tailm + (size_t)NTOK * HH;
    f16* Whp   = Bp + (size_t)HH * RR * HH;
    f16* Wtp   = Whp + (size_t)(DD / 32) * 8 * 512;

    prep_kernel<<<(HH * RR * HH) / 256, 256, 0, stream>>>(kern, Bp);
    dim3 wgrid((DD / 32) * 8 * 512 / 256, 2);
    prep_w<<<wgrid, 256, 0, stream>>>(Wh, Wt, Whp, Wtp);
    dim3 ffgrid(NTOK / 64, 2);
    ff_mfma<<<ffgrid, 256, 0, stream>>>(x, hid, root, Whp, bh, Wtp, bt, headm, tailm);
    biaffine_mfma<<<NTOK / 128, 512, 0, stream>>>(headm, tailm, Bp, out);
}